// Round 4
// baseline (123.516 us; speedup 1.0000x reference)
//
#include <hip/hip_runtime.h>
#include <cmath>

#define LFULL 8192
#define NH    4096
#define BIGI  8192
#define NPAD  (4096 + 128)   // +1 word per 32 words padding

__device__ __forceinline__ int padi(int w){ return w + (w >> 5); }

__device__ __forceinline__ float wmaxf(float v){
#pragma unroll
  for (int o = 32; o; o >>= 1) v = fmaxf(v, __shfl_xor(v, o));
  return v;
}
__device__ __forceinline__ float wminf(float v){
#pragma unroll
  for (int o = 32; o; o >>= 1) v = fminf(v, __shfl_xor(v, o));
  return v;
}
__device__ __forceinline__ float wsumf(float v){
#pragma unroll
  for (int o = 32; o; o >>= 1) v += __shfl_xor(v, o);
  return v;
}
__device__ __forceinline__ int wsumi(int v){
#pragma unroll
  for (int o = 32; o; o >>= 1) v += __shfl_xor(v, o);
  return v;
}
__device__ __forceinline__ int wmini(int v){
#pragma unroll
  for (int o = 32; o; o >>= 1) v = min(v, __shfl_xor(v, o));
  return v;
}
__device__ __forceinline__ int wmaxi(int v){
#pragma unroll
  for (int o = 32; o; o >>= 1) v = max(v, __shfl_xor(v, o));
  return v;
}

__device__ __forceinline__ unsigned mb16(int n){
  return (n <= 0) ? 0u : (n >= 16) ? 0xffffu : ((1u << n) - 1u);
}

// 8-point DFT with folded output twiddle: v[r] <- w^r * DFT8(v)_r.
// Structure: radix-2 split (b=even-out path, c=odd-out path with W8^d*w),
// then two DFT4s with uniform twiddle u^k (u = w^2).
template<int TW>
__device__ __forceinline__ void dft8(float* xr, float* xi, float wr, float wi){
  const float S = 0.70710678118654752f;
  float br[4], bi[4], cr4[4], ci4[4];
#pragma unroll
  for (int d = 0; d < 4; ++d){
    br[d]  = xr[d] + xr[d+4];  bi[d]  = xi[d] + xi[d+4];
    cr4[d] = xr[d] - xr[d+4];  ci4[d] = xi[d] - xi[d+4];
  }
  if (TW){
    // T_d = w * W8^d :  T0=w, T1=(p,q), T2=(wi,-wr), T3=(q,-p)
    float p = S*(wr + wi), q = S*(wi - wr), t;
    t = cr4[0]*wr - ci4[0]*wi;  ci4[0] = cr4[0]*wi + ci4[0]*wr;  cr4[0] = t;
    t = cr4[1]*p  - ci4[1]*q;   ci4[1] = cr4[1]*q  + ci4[1]*p;   cr4[1] = t;
    t = cr4[2]*wi + ci4[2]*wr;  ci4[2] = ci4[2]*wi - cr4[2]*wr;  cr4[2] = t;
    t = cr4[3]*q  + ci4[3]*p;   ci4[3] = ci4[3]*q  - cr4[3]*p;   cr4[3] = t;
  } else {
    // w = 1: T1=(S,-S), T2=-i, T3=(-S,-S)
    float t;
    t = S*(cr4[1] + ci4[1]);  ci4[1] = S*(ci4[1] - cr4[1]);  cr4[1] = t;
    t = ci4[2];               ci4[2] = -cr4[2];              cr4[2] = t;
    t = S*(ci4[3] - cr4[3]);  ci4[3] = -S*(cr4[3] + ci4[3]); cr4[3] = t;
  }
  float ur=1.f, ui=0.f, u2r=1.f, u2i=0.f, u3r=1.f, u3i=0.f;
  if (TW){
    ur  = wr*wr - wi*wi;    ui  = 2.f*wr*wi;
    u2r = ur*ur - ui*ui;    u2i = 2.f*ur*ui;
    u3r = u2r*ur - u2i*ui;  u3i = u2r*ui + u2i*ur;
  }
#pragma unroll
  for (int h = 0; h < 2; ++h){
    float* er = h ? cr4 : br;  float* ei = h ? ci4 : bi;
    float t0r = er[0]+er[2], t0i = ei[0]+ei[2];
    float t1r = er[0]-er[2], t1i = ei[0]-ei[2];
    float t2r = er[1]+er[3], t2i = ei[1]+ei[3];
    float t3r = er[1]-er[3], t3i = ei[1]-ei[3];
    float z0r = t0r+t2r, z0i = t0i+t2i;
    float z1r = t1r+t3i, z1i = t1i-t3r;    // t1 - i*t3
    float z2r = t0r-t2r, z2i = t0i-t2i;
    float z3r = t1r-t3i, z3i = t1i+t3r;    // t1 + i*t3
    if (TW){
      float s;
      s = z1r*ur  - z1i*ui;   z1i = z1r*ui  + z1i*ur;   z1r = s;
      s = z2r*u2r - z2i*u2i;  z2i = z2r*u2i + z2i*u2r;  z2r = s;
      s = z3r*u3r - z3i*u3i;  z3i = z3r*u3i + z3i*u3r;  z3r = s;
    }
    xr[0+h] = z0r;  xi[0+h] = z0i;
    xr[2+h] = z1r;  xi[2+h] = z1i;
    xr[4+h] = z2r;  xi[4+h] = z2i;
    xr[6+h] = z3r;  xi[6+h] = z3i;
  }
}

__global__ __launch_bounds__(512, 8)
void feat_kernel(const float* __restrict__ x, float* __restrict__ out){
  const int b = blockIdx.x;
  const float* __restrict__ row = x + (size_t)b * LFULL;

  __shared__ float re[NPAD], im[NPAD];   // packed: re=even samples, im=odd
  __shared__ float psum[512];            // per-thread chunk sums (16 elems each)
  __shared__ float sdA[8][4];
  __shared__ float sfA[8][2];
  __shared__ int   siA[8][6];
  __shared__ int   sb_i[4];              // P0, V0, V1, VL (gated)
  __shared__ float sb_hh;
  __shared__ int   sb_q[12];             // prefix-query indices
  __shared__ float qres[12];             // prefix-query results

  const int t    = threadIdx.x;
  const int lane = t & 63;
  const int wid  = t >> 6;
  const int base = t << 4;

  // ---------- load 16 contiguous samples -> regs + packed LDS ----------
  float v[16];
  const float4* __restrict__ rp = (const float4*)(row + base);
#pragma unroll
  for (int q = 0; q < 4; ++q){
    float4 f = rp[q];
    v[4*q] = f.x; v[4*q+1] = f.y; v[4*q+2] = f.z; v[4*q+3] = f.w;
  }
#pragma unroll
  for (int k = 0; k < 8; ++k){
    re[padi((t << 3) + k)] = v[2*k];
    im[padi((t << 3) + k)] = v[2*k+1];
  }
  __syncthreads();                       // S1

  // boundary neighbors from packed LDS (x[16t-1] odd -> im, x[16t+16] even -> re)
  const float xm_prev = (t > 0)   ? im[padi((t << 3) - 1)] : 0.f;
  const float xp_next = (t < 511) ? re[padi((t << 3) + 8)] : 0.f;

  // ---------- Phase A: stats + peak/valley bitmasks ----------
  float mx = -INFINITY, mn = INFINITY, sum = 0.f, sumsq = 0.f;
  unsigned pmask = 0u, vmask = 0u;
  float dprev = v[0] - xm_prev;
#pragma unroll
  for (int c = 0; c < 16; ++c){
    const float x0 = v[c];
    mx = fmaxf(mx, x0); mn = fminf(mn, x0);
    sum += x0; sumsq = fmaf(x0, x0, sumsq);
    const float xn = (c == 15) ? xp_next : v[(c == 15) ? 15 : c+1];
    const float d = xn - x0;
    pmask |= ((dprev > 0.f) & (d < 0.f)) ? (1u << c) : 0u;
    vmask |= ((dprev < 0.f) & (d > 0.f)) ? (1u << c) : 0u;
    dprev = d;
  }
  if (t == 0)  { pmask &= ~1u;     vmask &= ~1u; }
  if (t == 511){ pmask &= 0x7fffu; vmask &= 0x7fffu; }
  psum[t] = sum;                         // chunk sum for prefix queries

  int npk = __popc(pmask), nvl = __popc(vmask);
  int p0 = pmask ? base + __builtin_ctz(pmask) : BIGI;
  int va = vmask ? base + __builtin_ctz(vmask) : BIGI;
  unsigned vm2 = vmask & (vmask - 1u);
  int vb = vm2 ? base + __builtin_ctz(vm2) : BIGI;
  int vl = vmask ? base + 31 - __builtin_clz(vmask) : -1;

  mx = wmaxf(mx); mn = wminf(mn);
  sum = wsumf(sum); sumsq = wsumf(sumsq);
  npk = wsumi(npk); nvl = wsumi(nvl);
  p0 = wmini(p0); vl = wmaxi(vl);
#pragma unroll
  for (int o = 32; o; o >>= 1){          // two smallest valley indices
    int oa = __shfl_xor(va, o), ob = __shfl_xor(vb, o);
    int na = min(va, oa);
    int nb = min(max(va, oa), min(vb, ob));
    va = na; vb = nb;
  }
  if (lane == 0){
    sfA[wid][0] = mx;  sfA[wid][1] = mn;
    sdA[wid][0] = sum; sdA[wid][1] = sumsq;
    siA[wid][0] = npk; siA[wid][1] = nvl; siA[wid][2] = p0;
    siA[wid][3] = va;  siA[wid][4] = vb;  siA[wid][5] = vl;
  }
  __syncthreads();                       // S2

  int    t0_valid = 0;
  float  t0_ph = 0.f, t0_mx = 0.f, t0_mn = 0.f;
  double t0_sum = 0.0, t0_sumsq = 0.0;
  if (t == 0){
    mx = sfA[0][0]; mn = sfA[0][1];
    double dsum = sdA[0][0], dss = sdA[0][1];
    npk = siA[0][0]; nvl = siA[0][1]; p0 = siA[0][2];
    va = siA[0][3]; vb = siA[0][4]; vl = siA[0][5];
    for (int w = 1; w < 8; ++w){
      mx = fmaxf(mx, sfA[w][0]); mn = fminf(mn, sfA[w][1]);
      dsum += sdA[w][0]; dss += sdA[w][1];
      npk += siA[w][0]; nvl += siA[w][1];
      p0 = min(p0, siA[w][2]);
      int oa = siA[w][3], ob = siA[w][4];
      int na = min(va, oa);
      int nb = min(max(va, oa), min(vb, ob));
      va = na; vb = nb;
      vl = max(vl, siA[w][5]);
    }
    t0_valid = (npk >= 1) && (nvl >= 2);
    int P0 = t0_valid ? p0 : 0, V0 = t0_valid ? va : 0;
    int V1 = t0_valid ? vb : 0, VL = t0_valid ? vl : 0;
    sb_i[0] = P0; sb_i[1] = V0; sb_i[2] = V1; sb_i[3] = VL;
    float xp0 = (P0 & 1) ? im[padi(P0 >> 1)] : re[padi(P0 >> 1)];
    float xv0 = (V0 & 1) ? im[padi(V0 >> 1)] : re[padi(V0 >> 1)];
    sb_hh = 0.5f * (xp0 + xv0);
    t0_ph = xp0 - xv0;
    t0_sum = dsum; t0_sumsq = dss; t0_mx = mx; t0_mn = mn;
    // prefix-query indices for the 3 trapz windows
    int bu1 = max(VL - 2, V0 - 1);
    int bu2 = max(V1 - 2, P0 - 1);
    int bu3 = max(P0 - 2, V0 - 1);
    sb_q[0] = V0 - 1; sb_q[1] = V0; sb_q[2]  = bu1; sb_q[3]  = bu1 + 1;
    sb_q[4] = P0 - 1; sb_q[5] = P0; sb_q[6]  = bu2; sb_q[7]  = bu2 + 1;
    sb_q[8] = V0 - 1; sb_q[9] = V0; sb_q[10] = bu3; sb_q[11] = bu3 + 1;
  }
  __syncthreads();                       // S3
  const int   P0 = sb_i[0], V0 = sb_i[1];
  const float hh = sb_hh;

  // ---------- half-height li/ri via bitmask ----------
  {
    unsigned hhm = 0u;
#pragma unroll
    for (int c = 0; c < 16; ++c) hhm |= (v[c] >= hh) ? (1u << c) : 0u;
    unsigned rml = mb16(P0 - base)     & ~mb16(V0 - base);      // [V0, P0)
    unsigned rmr = mb16(P0 + 1 - base) & ~mb16(V0 + 1 - base);  // (V0, P0]
    unsigned ml  = hhm & rml, mr2 = hhm & rmr;
    int li = ml  ? base + __builtin_ctz(ml) : BIGI;
    int ri = mr2 ? base + 31 - __builtin_clz(mr2) : -1;
    li = wmini(li); ri = wmaxi(ri);
    if (lane == 0){ siA[wid][0] = li; siA[wid][1] = ri; }
  }

  // ---------- prefix-sum queries (one warp per query, 2 rounds) ----------
  {
    int qi = wid;
#pragma unroll
    for (int r = 0; r < 2; ++r, qi += 8){
      if (qi < 12){
        int q = sb_q[qi];
        float acc = 0.f;
        if (q >= 0){
          int cq = q >> 4;               // chunk holding index q
#pragma unroll
          for (int m = 0; m < 8; ++m){   // sum whole chunks below cq
            int tt = lane + (m << 6);
            float p = psum[tt];
            acc += (tt < cq) ? p : 0.f;
          }
          if (lane < 16 && lane <= (q & 15)){   // partial chunk cq
            int j = (cq << 4) + lane;
            acc += (j & 1) ? im[padi(j >> 1)] : re[padi(j >> 1)];
          }
        }
        acc = wsumf(acc);
        if (lane == 0) qres[qi] = acc;
      }
    }
  }
  __syncthreads();                       // S3b (qres ready; re/im reads done)

  // ---------- FFT: 4 register radix-8 phases (N=4096) ----------
  float ar8[8], ai8[8];
  // s0: i0 = t, q = 512, w = W4096^t
#pragma unroll
  for (int d = 0; d < 8; ++d){ int p = padi(t + (d << 9)); ar8[d] = re[p]; ai8[d] = im[p]; }
  { float swr, swi;
    __sincosf(-1.5339807878856412e-3f * (float)t, &swi, &swr);   // 2*pi/4096
    dft8<1>(ar8, ai8, swr, swi); }
#pragma unroll
  for (int d = 0; d < 8; ++d){ int p = padi(t + (d << 9)); re[p] = ar8[d]; im[p] = ai8[d]; }
  __syncthreads();                       // S4
  // s1: i0 = (t>>6)*512 + (t&63), q = 64, w = W512^(t&63)
  { const int i0 = ((t >> 6) << 9) + (t & 63);
#pragma unroll
    for (int d = 0; d < 8; ++d){ int p = padi(i0 + (d << 6)); ar8[d] = re[p]; ai8[d] = im[p]; }
    float swr, swi;
    __sincosf(-1.2271846303085130e-2f * (float)(t & 63), &swi, &swr);  // 2*pi/512
    dft8<1>(ar8, ai8, swr, swi);
#pragma unroll
    for (int d = 0; d < 8; ++d){ int p = padi(i0 + (d << 6)); re[p] = ar8[d]; im[p] = ai8[d]; }
  }
  __syncthreads();                       // S5
  // s2: i0 = (t>>3)*64 + (t&7), q = 8, w = W64^(t&7)
  { const int i0 = ((t >> 3) << 6) + (t & 7);
#pragma unroll
    for (int d = 0; d < 8; ++d){ int p = padi(i0 + (d << 3)); ar8[d] = re[p]; ai8[d] = im[p]; }
    float swr, swi;
    __sincosf(-9.8174770424681039e-2f * (float)(t & 7), &swi, &swr);   // 2*pi/64
    dft8<1>(ar8, ai8, swr, swi);
#pragma unroll
    for (int d = 0; d < 8; ++d){ int p = padi(i0 + (d << 3)); re[p] = ar8[d]; im[p] = ai8[d]; }
  }
  __syncthreads();                       // S6
  // s3: i0 = 8t, q = 1, w = 1; write octal-digit-reversed -> natural order
#pragma unroll
  for (int d = 0; d < 8; ++d){ int p = padi((t << 3) + d); ar8[d] = re[p]; ai8[d] = im[p]; }
  __syncthreads();                       // S6b (reads before scattered writes)
  dft8<0>(ar8, ai8, 1.f, 0.f);
  { const int R = ((t & 7) << 6) | (((t >> 3) & 7) << 3) | (t >> 6);
#pragma unroll
    for (int d = 0; d < 8; ++d){ int p = padi(R + (d << 9)); re[p] = ar8[d]; im[p] = ai8[d]; }
  }
  __syncthreads();                       // S7

  // ---------- Hermitian unpack + |X| sum (0.5 factors folded out) ----------
  float msum = 0.f;
  { float cwr, cwi;
    __sincosf(-7.6699039394282058e-4f * (float)t, &cwi, &cwr);   // W8192^t
    const float WSr = 0.92387953251128676f, WSi = -0.38268343236508977f; // W8192^512
#pragma unroll
    for (int c = 0; c < 8; ++c){
      int k  = t + (c << 9);
      int kk = (NH - k) & (NH - 1);
      float zr = re[padi(k)],  zi = im[padi(k)];
      float yr = re[padi(kk)], yi = im[padi(kk)];
      float er  = zr + yr, ei = zi - yi;     // 2*E
      float orr = zi + yi, oi = yr - zr;     // 2*O
      float tr = orr*cwr - oi*cwi, ti = orr*cwi + oi*cwr;
      float x1r = er + tr, x1i = ei + ti;    // 2*X[k]
      float x2r = er - tr, x2i = ei - ti;    // 2*X[k+4096]
      msum += sqrtf(x1r*x1r + x1i*x1i);
      msum += sqrtf(x2r*x2r + x2i*x2i);
      float nc = cwr*WSr - cwi*WSi;
      cwi = cwr*WSi + cwi*WSr; cwr = nc;
    }
  }
  msum = wsumf(msum);
  if (lane == 0) sdA[wid][3] = msum;
  __syncthreads();                       // S8

  if (t == 0){
    float msT = 0.f;
    int liT = BIGI, riT = -1;
    for (int w = 0; w < 8; ++w){
      msT += sdA[w][3];
      liT = min(liT, siA[w][0]);
      riT = max(riT, siA[w][1]);
    }
    double n = (double)LFULL;
    double var = (t0_sumsq - t0_sum * t0_sum / n) / (n - 1.0);
    float F0 = t0_mx, F1 = t0_mx - t0_mn, F2 = (float)var, F3 = (float)sqrt(var);
    float F4 = msT * (1.f / 16384.f);    // /2 (fold) /8192 (mean)
    float F5 = 0.f, F6 = 0.f, F7 = 0.f, F8 = 0.f, F9 = 0.f;
    if (t0_valid){
      const float C = 0.5f / 30.0f;
      F5 = C * ((qres[2]  - qres[0]) + (qres[3]  - qres[1]));
      F6 = C * ((qres[6]  - qres[4]) + (qres[7]  - qres[5]));
      F8 = C * ((qres[10] - qres[8]) + (qres[11] - qres[9]));
      F7 = t0_ph;
      int LI = (liT == BIGI) ? sb_i[1] : liT;
      int RI = (riT == -1)   ? sb_i[0] : riT;
      F9 = (float)(RI - LI) / 30.0f;
    }
    float* __restrict__ o = out + (size_t)b * 10;
    o[0]=F0; o[1]=F1; o[2]=F2; o[3]=F3; o[4]=F4;
    o[5]=F5; o[6]=F6; o[7]=F7; o[8]=F8; o[9]=F9;
  }
}

extern "C" void kernel_launch(void* const* d_in, const int* in_sizes, int n_in,
                              void* d_out, int out_size, void* d_ws, size_t ws_size,
                              hipStream_t stream){
  const float* x = (const float*)d_in[0];
  float* out = (float*)d_out;
  int nrows = in_sizes[0] / LFULL;
  hipLaunchKernelGGL(feat_kernel, dim3(nrows), dim3(512), 0, stream, x, out);
}

// Round 5
// 112.373 us; speedup vs baseline: 1.0992x; 1.0992x over previous
//
#include <hip/hip_runtime.h>
#include <cmath>

#define LFULL 8192
#define NH    4096
#define BIGI  8192

// complex index -> padded complex index (+1 complex per 16 complex)
__device__ __forceinline__ int cpad(int k){ return k + (k >> 4); }

__device__ __forceinline__ float wmaxf(float v){
#pragma unroll
  for (int o = 32; o; o >>= 1) v = fmaxf(v, __shfl_xor(v, o));
  return v;
}
__device__ __forceinline__ float wminf(float v){
#pragma unroll
  for (int o = 32; o; o >>= 1) v = fminf(v, __shfl_xor(v, o));
  return v;
}
__device__ __forceinline__ float wsumf(float v){
#pragma unroll
  for (int o = 32; o; o >>= 1) v += __shfl_xor(v, o);
  return v;
}
__device__ __forceinline__ int wsumi(int v){
#pragma unroll
  for (int o = 32; o; o >>= 1) v += __shfl_xor(v, o);
  return v;
}
__device__ __forceinline__ int wmini(int v){
#pragma unroll
  for (int o = 32; o; o >>= 1) v = min(v, __shfl_xor(v, o));
  return v;
}
__device__ __forceinline__ int wmaxi(int v){
#pragma unroll
  for (int o = 32; o; o >>= 1) v = max(v, __shfl_xor(v, o));
  return v;
}

__device__ __forceinline__ unsigned mb32(int n){
  return (n <= 0) ? 0u : (n >= 32) ? 0xffffffffu : ((1u << n) - 1u);
}

// 16-point DFT = two radix-4 DIF layers in registers, output twiddle folded:
// out[r] = w^r * DFT16(in)_r.  (verified correct in Round 3)
__device__ __forceinline__ void dft16(float* vr, float* vi, float wr, float wi){
  const float OR[10] = {1.f, 0.9238795325112867f, 0.7071067811865476f, 0.3826834323650898f,
                        0.f, 0.f, -0.7071067811865476f, 0.f, 0.f, -0.9238795325112867f};
  const float OI[10] = {0.f,-0.3826834323650898f,-0.7071067811865476f,-0.9238795325112867f,
                       -1.f, 0.f, -0.7071067811865476f, 0.f, 0.f, 0.3826834323650898f};
  const float w2r = wr*wr - wi*wi,  w2i = 2.f*wr*wi;
  const float w3r = w2r*wr - w2i*wi, w3i = w2r*wi + w2i*wr;
  const float prt[4] = {1.f, wr, w2r, w3r};
  const float pit[4] = {0.f, wi, w2i, w3i};
#pragma unroll
  for (int d = 0; d < 4; ++d){
    float t0r = vr[d]    + vr[d+8],  t0i = vi[d]    + vi[d+8];
    float t1r = vr[d]    - vr[d+8],  t1i = vi[d]    - vi[d+8];
    float t2r = vr[d+4]  + vr[d+12], t2i = vi[d+4]  + vi[d+12];
    float t3r = vr[d+4]  - vr[d+12], t3i = vi[d+4]  - vi[d+12];
    float u0r = t0r + t2r, u0i = t0i + t2i;
    float u2r = t0r - t2r, u2i = t0i - t2i;
    float u1r = t1r + t3i, u1i = t1i - t3r;   // t1 - i*t3
    float u3r = t1r - t3i, u3i = t1i + t3r;   // t1 + i*t3
    float T1r = prt[1]*OR[d]   - pit[1]*OI[d];
    float T1i = prt[1]*OI[d]   + pit[1]*OR[d];
    float T2r = prt[2]*OR[2*d] - pit[2]*OI[2*d];
    float T2i = prt[2]*OI[2*d] + pit[2]*OR[2*d];
    float T3r = prt[3]*OR[3*d] - pit[3]*OI[3*d];
    float T3i = prt[3]*OI[3*d] + pit[3]*OR[3*d];
    vr[d]    = u0r;                 vi[d]    = u0i;
    vr[d+4]  = u1r*T1r - u1i*T1i;   vi[d+4]  = u1r*T1i + u1i*T1r;
    vr[d+8]  = u2r*T2r - u2i*T2i;   vi[d+8]  = u2r*T2i + u2i*T2r;
    vr[d+12] = u3r*T3r - u3i*T3i;   vi[d+12] = u3r*T3i + u3i*T3r;
  }
  const float U1r = w2r*w2r - w2i*w2i, U1i = 2.f*w2r*w2i;        // w^4
  const float U2r = U1r*U1r - U1i*U1i, U2i = 2.f*U1r*U1i;        // w^8
  const float U3r = U2r*U1r - U2i*U1i, U3i = U2r*U1i + U2i*U1r;  // w^12
#pragma unroll
  for (int g = 0; g < 4; ++g){
    const int i0 = 4*g;
    float t0r = vr[i0]   + vr[i0+2], t0i = vi[i0]   + vi[i0+2];
    float t1r = vr[i0]   - vr[i0+2], t1i = vi[i0]   - vi[i0+2];
    float t2r = vr[i0+1] + vr[i0+3], t2i = vi[i0+1] + vi[i0+3];
    float t3r = vr[i0+1] - vr[i0+3], t3i = vi[i0+1] - vi[i0+3];
    float u0r = t0r + t2r, u0i = t0i + t2i;
    float u2r = t0r - t2r, u2i = t0i - t2i;
    float u1r = t1r + t3i, u1i = t1i - t3r;
    float u3r = t1r - t3i, u3i = t1i + t3r;
    vr[i0]   = u0r;                 vi[i0]   = u0i;
    vr[i0+1] = u1r*U1r - u1i*U1i;   vi[i0+1] = u1r*U1i + u1i*U1r;
    vr[i0+2] = u2r*U2r - u2i*U2i;   vi[i0+2] = u2r*U2i + u2i*U2r;
    vr[i0+3] = u3r*U3r - u3i*U3i;   vi[i0+3] = u3r*U3i + u3i*U3r;
  }
}

__global__ __launch_bounds__(256, 4)
void feat_kernel(const float* __restrict__ x, float* __restrict__ out){
  const int b = blockIdx.x;
  const float* __restrict__ row = x + (size_t)b * LFULL;

  __shared__ float2 cx[4352];            // 4096 complex + 256 pad
  __shared__ float  psum[256];           // per-thread 32-sample chunk sums
  __shared__ float  sdA[4][4];
  __shared__ float  sfA[4][2];
  __shared__ int    siA[4][6];
  __shared__ int    sb_i[4];             // P0, V0, V1, VL (gated)
  __shared__ float  sb_hh;
  __shared__ int    sb_q[12];
  __shared__ float  qres[12];

  const int t    = threadIdx.x;
  const int lane = t & 63;
  const int wid  = t >> 6;
  const int base = t << 5;               // first sample index of this thread

  // ---------- load 32 contiguous samples -> regs + packed complex LDS ----------
  float v[32];
  const float4* __restrict__ rp = (const float4*)(row + base);
#pragma unroll
  for (int q = 0; q < 8; ++q){
    float4 f = rp[q];
    v[4*q] = f.x; v[4*q+1] = f.y; v[4*q+2] = f.z; v[4*q+3] = f.w;
  }
#pragma unroll
  for (int c = 0; c < 16; ++c)
    cx[cpad((t << 4) + c)] = make_float2(v[2*c], v[2*c+1]);
  __syncthreads();                       // S1

  const float xm_prev = (t > 0)   ? cx[cpad((t << 4) - 1)].y  : v[0];
  const float xp_next = (t < 255) ? cx[cpad((t << 4) + 16)].x : v[31];

  // ---------- Phase A: stats + peak/valley bitmasks (32-bit) ----------
  float mx = -INFINITY, mn = INFINITY, sum = 0.f, sumsq = 0.f;
  unsigned pmask = 0u, vmask = 0u;
  float dprev = v[0] - xm_prev;
#pragma unroll
  for (int c = 0; c < 32; ++c){
    const float x0 = v[c];
    mx = fmaxf(mx, x0); mn = fminf(mn, x0);
    sum += x0; sumsq = fmaf(x0, x0, sumsq);
    const float xn = (c == 31) ? xp_next : v[(c == 31) ? 31 : c+1];
    const float d = xn - x0;
    pmask |= ((dprev > 0.f) & (d < 0.f)) ? (1u << c) : 0u;
    vmask |= ((dprev < 0.f) & (d > 0.f)) ? (1u << c) : 0u;
    dprev = d;
  }
  if (t == 0)  { pmask &= ~1u;          vmask &= ~1u; }
  if (t == 255){ pmask &= 0x7fffffffu;  vmask &= 0x7fffffffu; }
  psum[t] = sum;

  int npk = __popc(pmask), nvl = __popc(vmask);
  int p0 = pmask ? base + __builtin_ctz(pmask) : BIGI;
  int va = vmask ? base + __builtin_ctz(vmask) : BIGI;
  unsigned vm2 = vmask & (vmask - 1u);
  int vb = vm2 ? base + __builtin_ctz(vm2) : BIGI;
  int vl = vmask ? base + 31 - __builtin_clz(vmask) : -1;

  mx = wmaxf(mx); mn = wminf(mn);
  sum = wsumf(sum); sumsq = wsumf(sumsq);
  npk = wsumi(npk); nvl = wsumi(nvl);
  p0 = wmini(p0); vl = wmaxi(vl);
#pragma unroll
  for (int o = 32; o; o >>= 1){          // two smallest valley indices
    int oa = __shfl_xor(va, o), ob = __shfl_xor(vb, o);
    int na = min(va, oa);
    int nb = min(max(va, oa), min(vb, ob));
    va = na; vb = nb;
  }
  if (lane == 0){
    sfA[wid][0] = mx;  sfA[wid][1] = mn;
    sdA[wid][0] = sum; sdA[wid][1] = sumsq;
    siA[wid][0] = npk; siA[wid][1] = nvl; siA[wid][2] = p0;
    siA[wid][3] = va;  siA[wid][4] = vb;  siA[wid][5] = vl;
  }
  __syncthreads();                       // S2

  int    t0_valid = 0;
  float  t0_ph = 0.f, t0_mx = 0.f, t0_mn = 0.f;
  double t0_sum = 0.0, t0_sumsq = 0.0;
  if (t == 0){
    mx = sfA[0][0]; mn = sfA[0][1];
    double dsum = sdA[0][0], dss = sdA[0][1];
    npk = siA[0][0]; nvl = siA[0][1]; p0 = siA[0][2];
    va = siA[0][3]; vb = siA[0][4]; vl = siA[0][5];
    for (int w = 1; w < 4; ++w){
      mx = fmaxf(mx, sfA[w][0]); mn = fminf(mn, sfA[w][1]);
      dsum += sdA[w][0]; dss += sdA[w][1];
      npk += siA[w][0]; nvl += siA[w][1];
      p0 = min(p0, siA[w][2]);
      int oa = siA[w][3], ob = siA[w][4];
      int na = min(va, oa);
      int nb = min(max(va, oa), min(vb, ob));
      va = na; vb = nb;
      vl = max(vl, siA[w][5]);
    }
    t0_valid = (npk >= 1) && (nvl >= 2);
    int P0 = t0_valid ? p0 : 0, V0 = t0_valid ? va : 0;
    int V1 = t0_valid ? vb : 0, VL = t0_valid ? vl : 0;
    sb_i[0] = P0; sb_i[1] = V0; sb_i[2] = V1; sb_i[3] = VL;
    float2 cp = cx[cpad(P0 >> 1)], cv = cx[cpad(V0 >> 1)];
    float xp0 = (P0 & 1) ? cp.y : cp.x;
    float xv0 = (V0 & 1) ? cv.y : cv.x;
    sb_hh = 0.5f * (xp0 + xv0);
    t0_ph = xp0 - xv0;
    t0_sum = dsum; t0_sumsq = dss; t0_mx = mx; t0_mn = mn;
    int bu1 = max(VL - 2, V0 - 1);
    int bu2 = max(V1 - 2, P0 - 1);
    int bu3 = max(P0 - 2, V0 - 1);
    sb_q[0] = V0 - 1; sb_q[1] = V0; sb_q[2]  = bu1; sb_q[3]  = bu1 + 1;
    sb_q[4] = P0 - 1; sb_q[5] = P0; sb_q[6]  = bu2; sb_q[7]  = bu2 + 1;
    sb_q[8] = V0 - 1; sb_q[9] = V0; sb_q[10] = bu3; sb_q[11] = bu3 + 1;
  }
  __syncthreads();                       // S3
  const int   P0 = sb_i[0], V0 = sb_i[1];
  const float hh = sb_hh;

  // ---------- half-height li/ri via 32-bit bitmask ----------
  {
    unsigned hhm = 0u;
#pragma unroll
    for (int c = 0; c < 32; ++c) hhm |= (v[c] >= hh) ? (1u << c) : 0u;
    unsigned rml = mb32(P0 - base)     & ~mb32(V0 - base);      // [V0, P0)
    unsigned rmr = mb32(P0 + 1 - base) & ~mb32(V0 + 1 - base);  // (V0, P0]
    unsigned ml  = hhm & rml, mr2 = hhm & rmr;
    int li = ml  ? base + __builtin_ctz(ml) : BIGI;
    int ri = mr2 ? base + 31 - __builtin_clz(mr2) : -1;
    li = wmini(li); ri = wmaxi(ri);
    if (lane == 0){ siA[wid][0] = li; siA[wid][1] = ri; }
  }

  // ---------- prefix-sum queries: Q[q] = sum x[0..q] (one warp per query) ----------
  {
    int qi = wid;
#pragma unroll
    for (int r = 0; r < 3; ++r, qi += 4){
      if (qi < 12){
        int q = sb_q[qi];
        float acc = 0.f;
        if (q >= 0){
          int cq = q >> 5;                      // owning chunk (thread)
#pragma unroll
          for (int m = 0; m < 4; ++m){
            int tt = lane + (m << 6);
            float p = psum[tt];
            acc += (tt < cq) ? p : 0.f;
          }
          if (lane < 32 && lane <= (q & 31)){   // partial chunk
            float2 cc = cx[cpad((cq << 4) + (lane >> 1))];
            acc += (lane & 1) ? cc.y : cc.x;
          }
        }
        acc = wsumf(acc);
        if (lane == 0) qres[qi] = acc;
      }
    }
  }
  __syncthreads();                       // S3b: all signal reads done

  // ---------- FFT: 3 register radix-16 stages (N=4096) ----------
  float ar[16], ai[16];
  // stage 0: k = t + 256 d, w = W4096^t
#pragma unroll
  for (int d = 0; d < 16; ++d){ float2 c = cx[cpad(t + (d << 8))]; ar[d] = c.x; ai[d] = c.y; }
  { float swr, swi;
    __sincosf(-1.5339807878856412e-3f * (float)t, &swi, &swr);   // -2pi/4096
    dft16(ar, ai, swr, swi); }
#pragma unroll
  for (int d = 0; d < 16; ++d) cx[cpad(t + (d << 8))] = make_float2(ar[d], ai[d]);
  __syncthreads();                       // S4
  // stage 1: k = (t>>4)*256 + (t&15) + 16 d, w = W256^(t&15)
  { const int i0 = ((t >> 4) << 8) + (t & 15);
#pragma unroll
    for (int d = 0; d < 16; ++d){ float2 c = cx[cpad(i0 + (d << 4))]; ar[d] = c.x; ai[d] = c.y; }
    float swr, swi;
    __sincosf(-2.4543692606170259e-2f * (float)(t & 15), &swi, &swr);  // -2pi/256
    dft16(ar, ai, swr, swi);
#pragma unroll
    for (int d = 0; d < 16; ++d) cx[cpad(i0 + (d << 4))] = make_float2(ar[d], ai[d]);
  }
  __syncthreads();                       // S5
  // stage 2: k = 16 t + d, w = 1; scatter-write to natural order
#pragma unroll
  for (int d = 0; d < 16; ++d){ float2 c = cx[cpad((t << 4) + d)]; ar[d] = c.x; ai[d] = c.y; }
  __syncthreads();                       // S6: all reads before scattered writes
  dft16(ar, ai, 1.f, 0.f);
  const int M = ((t & 3) << 6) | (((t >> 2) & 3) << 4) | (((t >> 4) & 3) << 2) | (t >> 6);
#pragma unroll
  for (int s = 0; s < 16; ++s){
    const int r = ((s & 3) << 2) | (s >> 2);
    cx[cpad((s << 8) + M)] = make_float2(ar[r], ai[r]);   // == drev12(16t+r)
  }
  __syncthreads();                       // S7: natural-order Z[k] in cx

  // ---------- fused Hermitian unpack + |X| sum (own regs + partner reads) ----------
  float msum = 0.f;
  { float cwr, cwi;
    __sincosf(-7.6699039394282058e-4f * (float)M, &cwi, &cwr);   // W8192^M
    const float WSr = 0.98078528040323044f, WSi = -0.19509032201612827f; // W8192^256
#pragma unroll
    for (int s = 0; s < 16; ++s){
      const int r = ((s & 3) << 2) | (s >> 2);
      const float zr = ar[r], zi = ai[r];                  // Z[256 s + M]
      const int kk = (((15 - s) << 8) + 256 - M) & (NH - 1);
      float2 y = cx[cpad(kk)];                             // Z[(4096 - k) mod 4096]
      float er  = zr + y.x, ei = zi - y.y;                 // 2 E
      float orr = zi + y.y, oi = y.x - zr;                 // 2 O
      float tr = orr*cwr - oi*cwi, ti = orr*cwi + oi*cwr;
      float x1r = er + tr, x1i = ei + ti;                  // 2 X[k]
      float x2r = er - tr, x2i = ei - ti;                  // 2 X[k+4096]
      msum += __builtin_amdgcn_sqrtf(x1r*x1r + x1i*x1i);
      msum += __builtin_amdgcn_sqrtf(x2r*x2r + x2i*x2i);
      float nc = cwr*WSr - cwi*WSi;
      cwi = cwr*WSi + cwi*WSr; cwr = nc;
    }
  }
  msum = wsumf(msum);
  if (lane == 0) sdA[wid][3] = msum;
  __syncthreads();                       // S8

  if (t == 0){
    float msT = sdA[0][3] + sdA[1][3] + sdA[2][3] + sdA[3][3];
    int liT = min(min(siA[0][0], siA[1][0]), min(siA[2][0], siA[3][0]));
    int riT = max(max(siA[0][1], siA[1][1]), max(siA[2][1], siA[3][1]));
    double n = (double)LFULL;
    double var = (t0_sumsq - t0_sum * t0_sum / n) / (n - 1.0);
    float F0 = t0_mx, F1 = t0_mx - t0_mn, F2 = (float)var, F3 = (float)sqrt(var);
    float F4 = msT * (1.f / 16384.f);    // /2 (fold) /8192 (mean)
    float F5 = 0.f, F6 = 0.f, F7 = 0.f, F8 = 0.f, F9 = 0.f;
    if (t0_valid){
      const float C = 0.5f / 30.0f;
      F5 = C * ((qres[2]  - qres[0]) + (qres[3]  - qres[1]));
      F6 = C * ((qres[6]  - qres[4]) + (qres[7]  - qres[5]));
      F8 = C * ((qres[10] - qres[8]) + (qres[11] - qres[9]));
      F7 = t0_ph;
      int LI = (liT == BIGI) ? sb_i[1] : liT;
      int RI = (riT == -1)   ? sb_i[0] : riT;
      F9 = (float)(RI - LI) / 30.0f;
    }
    float* __restrict__ o = out + (size_t)b * 10;
    o[0]=F0; o[1]=F1; o[2]=F2; o[3]=F3; o[4]=F4;
    o[5]=F5; o[6]=F6; o[7]=F7; o[8]=F8; o[9]=F9;
  }
}

extern "C" void kernel_launch(void* const* d_in, const int* in_sizes, int n_in,
                              void* d_out, int out_size, void* d_ws, size_t ws_size,
                              hipStream_t stream){
  const float* x = (const float*)d_in[0];
  float* out = (float*)d_out;
  int nrows = in_sizes[0] / LFULL;
  hipLaunchKernelGGL(feat_kernel, dim3(nrows), dim3(256), 0, stream, x, out);
}

// Round 6
// 110.728 us; speedup vs baseline: 1.1155x; 1.0149x over previous
//
#include <hip/hip_runtime.h>
#include <cmath>

#define LFULL 8192
#define NH    4096
#define BIGI  8192

typedef float f2 __attribute__((ext_vector_type(2)));

__device__ __forceinline__ f2 mkf2(float a, float b){ f2 r; r.x = a; r.y = b; return r; }
// complex multiply: (a.x+i a.y)(b.x+i b.y)  -> 1 pk_mul + 1 pk_fma
__device__ __forceinline__ f2 cmul(f2 a, f2 b){
  f2 p = mkf2(a.x, a.x) * b;
  return __builtin_elementwise_fma(mkf2(a.y, a.y), mkf2(-b.y, b.x), p);
}
// -i * t
__device__ __forceinline__ f2 nimul(f2 t){ return mkf2(t.y, -t.x); }

// complex index -> padded complex index (+1 complex per 16)
__device__ __forceinline__ int cpad(int k){ return k + (k >> 4); }

__device__ __forceinline__ float wmaxf(float v){
#pragma unroll
  for (int o = 32; o; o >>= 1) v = fmaxf(v, __shfl_xor(v, o));
  return v;
}
__device__ __forceinline__ float wminf(float v){
#pragma unroll
  for (int o = 32; o; o >>= 1) v = fminf(v, __shfl_xor(v, o));
  return v;
}
__device__ __forceinline__ float wsumf(float v){
#pragma unroll
  for (int o = 32; o; o >>= 1) v += __shfl_xor(v, o);
  return v;
}
__device__ __forceinline__ int wsumi(int v){
#pragma unroll
  for (int o = 32; o; o >>= 1) v += __shfl_xor(v, o);
  return v;
}
__device__ __forceinline__ int wmini(int v){
#pragma unroll
  for (int o = 32; o; o >>= 1) v = min(v, __shfl_xor(v, o));
  return v;
}
__device__ __forceinline__ int wmaxi(int v){
#pragma unroll
  for (int o = 32; o; o >>= 1) v = max(v, __shfl_xor(v, o));
  return v;
}
__device__ __forceinline__ unsigned mb32(int n){
  return (n <= 0) ? 0u : (n >= 32) ? 0xffffffffu : ((1u << n) - 1u);
}

// 16-point DFT (two radix-4 DIF layers), output twiddle folded:
// out[r] = w^r * DFT16(in)_r.  Same math as Round 5 (verified), f2-packed.
__device__ __forceinline__ void dft16(f2* v, f2 w){
  const float OR[10] = {1.f, 0.9238795325112867f, 0.7071067811865476f, 0.3826834323650898f,
                        0.f, 0.f, -0.7071067811865476f, 0.f, 0.f, -0.9238795325112867f};
  const float OI[10] = {0.f,-0.3826834323650898f,-0.7071067811865476f,-0.9238795325112867f,
                       -1.f, 0.f, -0.7071067811865476f, 0.f, 0.f, 0.3826834323650898f};
  const f2 w2 = cmul(w, w);
  const f2 w3 = cmul(w2, w);
#pragma unroll
  for (int d = 0; d < 4; ++d){
    f2 t0 = v[d]    + v[d+8];
    f2 t1 = v[d]    - v[d+8];
    f2 t2 = v[d+4]  + v[d+12];
    f2 t3 = v[d+4]  - v[d+12];
    f2 n3 = nimul(t3);
    f2 u0 = t0 + t2;
    f2 u2 = t0 - t2;
    f2 u1 = t1 + n3;
    f2 u3 = t1 - n3;
    f2 T1 = cmul(w,  mkf2(OR[d],   OI[d]));
    f2 T2 = cmul(w2, mkf2(OR[2*d], OI[2*d]));
    f2 T3 = cmul(w3, mkf2(OR[3*d], OI[3*d]));
    v[d]    = u0;
    v[d+4]  = cmul(u1, T1);
    v[d+8]  = cmul(u2, T2);
    v[d+12] = cmul(u3, T3);
  }
  const f2 U1 = cmul(w2, w2);
  const f2 U2 = cmul(U1, U1);
  const f2 U3 = cmul(U2, U1);
#pragma unroll
  for (int g = 0; g < 4; ++g){
    const int i0 = 4*g;
    f2 t0 = v[i0]   + v[i0+2];
    f2 t1 = v[i0]   - v[i0+2];
    f2 t2 = v[i0+1] + v[i0+3];
    f2 t3 = v[i0+1] - v[i0+3];
    f2 n3 = nimul(t3);
    f2 z0 = t0 + t2;
    f2 z1 = t1 + n3;
    f2 z2 = t0 - t2;
    f2 z3 = t1 - n3;
    v[i0]   = z0;
    v[i0+1] = cmul(z1, U1);
    v[i0+2] = cmul(z2, U2);
    v[i0+3] = cmul(z3, U3);
  }
}

__global__ __launch_bounds__(256, 4)
void feat_kernel(const float* __restrict__ x, float* __restrict__ out){
  const int b = blockIdx.x;
  const float* __restrict__ row = x + (size_t)b * LFULL;

  __shared__ f2    cx[4352];             // 4096 complex + 256 pad
  __shared__ float psum[256];            // per-thread 32-sample chunk sums
  __shared__ float sdA[4][4];
  __shared__ float sfA[4][2];
  __shared__ int   siA[4][6];
  __shared__ int   sb_i[4];              // P0, V0, V1, VL (gated)
  __shared__ float sb_hh;
  __shared__ int   sb_q[12];
  __shared__ float qres[12];

  const int t    = threadIdx.x;
  const int lane = t & 63;
  const int wid  = t >> 6;
  const int base = t << 5;               // first sample index of this thread

  // ---------- load 32 contiguous samples as 16 complex pairs ----------
  f2 vv[16];
  const float4* __restrict__ rp = (const float4*)(row + base);
#pragma unroll
  for (int q = 0; q < 8; ++q){
    float4 f = rp[q];
    vv[2*q]   = mkf2(f.x, f.y);
    vv[2*q+1] = mkf2(f.z, f.w);
  }
#pragma unroll
  for (int c = 0; c < 16; ++c)
    cx[cpad((t << 4) + c)] = vv[c];
  __syncthreads();                       // S1

  const float xm_prev = (t > 0)   ? cx[cpad((t << 4) - 1)].y  : vv[0].x;
  const float xp_next = (t < 255) ? cx[cpad((t << 4) + 16)].x : vv[15].y;

  // ---------- Phase A: packed stats + peak/valley bitmasks ----------
  f2 mx2 = mkf2(-INFINITY, -INFINITY), mn2 = mkf2(INFINITY, INFINITY);
  f2 sum2 = mkf2(0.f, 0.f), ss2 = mkf2(0.f, 0.f);
  unsigned pmask = 0u, vmask = 0u;
  float dprev = vv[0].x - xm_prev;
#pragma unroll
  for (int c = 0; c < 16; ++c){
    const f2 u = vv[c];
    mx2 = __builtin_elementwise_max(mx2, u);
    mn2 = __builtin_elementwise_min(mn2, u);
    sum2 += u;
    ss2 = __builtin_elementwise_fma(u, u, ss2);
    const float d0 = u.y - u.x;
    const float xnext = (c < 15) ? vv[(c + 1) & 15].x : xp_next;
    const float d1 = xnext - u.y;
    pmask |= ((dprev > 0.f) & (d0 < 0.f)) ? (1u << (2*c))   : 0u;
    vmask |= ((dprev < 0.f) & (d0 > 0.f)) ? (1u << (2*c))   : 0u;
    pmask |= ((d0 > 0.f) & (d1 < 0.f))    ? (1u << (2*c+1)) : 0u;
    vmask |= ((d0 < 0.f) & (d1 > 0.f))    ? (1u << (2*c+1)) : 0u;
    dprev = d1;
  }
  if (t == 0)  { pmask &= ~1u;          vmask &= ~1u; }
  if (t == 255){ pmask &= 0x7fffffffu;  vmask &= 0x7fffffffu; }
  float csum = sum2.x + sum2.y;
  psum[t] = csum;

  float mx = fmaxf(mx2.x, mx2.y), mn = fminf(mn2.x, mn2.y);
  float sum = csum, sumsq = ss2.x + ss2.y;
  int npk = __popc(pmask), nvl = __popc(vmask);
  int p0 = pmask ? base + __builtin_ctz(pmask) : BIGI;
  int va = vmask ? base + __builtin_ctz(vmask) : BIGI;
  unsigned vm2m = vmask & (vmask - 1u);
  int vb = vm2m ? base + __builtin_ctz(vm2m) : BIGI;
  int vl = vmask ? base + 31 - __builtin_clz(vmask) : -1;

  mx = wmaxf(mx); mn = wminf(mn);
  sum = wsumf(sum); sumsq = wsumf(sumsq);
  npk = wsumi(npk); nvl = wsumi(nvl);
  p0 = wmini(p0); vl = wmaxi(vl);
#pragma unroll
  for (int o = 32; o; o >>= 1){          // two smallest valley indices
    int oa = __shfl_xor(va, o), ob = __shfl_xor(vb, o);
    int na = min(va, oa);
    int nb = min(max(va, oa), min(vb, ob));
    va = na; vb = nb;
  }
  if (lane == 0){
    sfA[wid][0] = mx;  sfA[wid][1] = mn;
    sdA[wid][0] = sum; sdA[wid][1] = sumsq;
    siA[wid][0] = npk; siA[wid][1] = nvl; siA[wid][2] = p0;
    siA[wid][3] = va;  siA[wid][4] = vb;  siA[wid][5] = vl;
  }
  __syncthreads();                       // S2

  int    t0_valid = 0;
  float  t0_ph = 0.f, t0_mx = 0.f, t0_mn = 0.f;
  double t0_sum = 0.0, t0_sumsq = 0.0;
  if (t == 0){
    mx = sfA[0][0]; mn = sfA[0][1];
    double dsum = sdA[0][0], dss = sdA[0][1];
    npk = siA[0][0]; nvl = siA[0][1]; p0 = siA[0][2];
    va = siA[0][3]; vb = siA[0][4]; vl = siA[0][5];
    for (int w = 1; w < 4; ++w){
      mx = fmaxf(mx, sfA[w][0]); mn = fminf(mn, sfA[w][1]);
      dsum += sdA[w][0]; dss += sdA[w][1];
      npk += siA[w][0]; nvl += siA[w][1];
      p0 = min(p0, siA[w][2]);
      int oa = siA[w][3], ob = siA[w][4];
      int na = min(va, oa);
      int nb = min(max(va, oa), min(vb, ob));
      va = na; vb = nb;
      vl = max(vl, siA[w][5]);
    }
    t0_valid = (npk >= 1) && (nvl >= 2);
    int P0 = t0_valid ? p0 : 0, V0 = t0_valid ? va : 0;
    int V1 = t0_valid ? vb : 0, VL = t0_valid ? vl : 0;
    sb_i[0] = P0; sb_i[1] = V0; sb_i[2] = V1; sb_i[3] = VL;
    f2 cp = cx[cpad(P0 >> 1)], cv = cx[cpad(V0 >> 1)];
    float xp0 = (P0 & 1) ? cp.y : cp.x;
    float xv0 = (V0 & 1) ? cv.y : cv.x;
    sb_hh = 0.5f * (xp0 + xv0);
    t0_ph = xp0 - xv0;
    t0_sum = dsum; t0_sumsq = dss; t0_mx = mx; t0_mn = mn;
    int bu1 = max(VL - 2, V0 - 1);
    int bu2 = max(V1 - 2, P0 - 1);
    int bu3 = max(P0 - 2, V0 - 1);
    sb_q[0] = V0 - 1; sb_q[1] = V0; sb_q[2]  = bu1; sb_q[3]  = bu1 + 1;
    sb_q[4] = P0 - 1; sb_q[5] = P0; sb_q[6]  = bu2; sb_q[7]  = bu2 + 1;
    sb_q[8] = V0 - 1; sb_q[9] = V0; sb_q[10] = bu3; sb_q[11] = bu3 + 1;
  }
  __syncthreads();                       // S3
  const int   P0 = sb_i[0], V0 = sb_i[1];
  const float hh = sb_hh;

  // ---------- half-height li/ri via 32-bit bitmask ----------
  {
    unsigned hhm = 0u;
#pragma unroll
    for (int c = 0; c < 16; ++c){
      hhm |= (vv[c].x >= hh) ? (1u << (2*c))   : 0u;
      hhm |= (vv[c].y >= hh) ? (1u << (2*c+1)) : 0u;
    }
    unsigned rml = mb32(P0 - base)     & ~mb32(V0 - base);      // [V0, P0)
    unsigned rmr = mb32(P0 + 1 - base) & ~mb32(V0 + 1 - base);  // (V0, P0]
    unsigned ml  = hhm & rml, mr2 = hhm & rmr;
    int li = ml  ? base + __builtin_ctz(ml) : BIGI;
    int ri = mr2 ? base + 31 - __builtin_clz(mr2) : -1;
    li = wmini(li); ri = wmaxi(ri);
    if (lane == 0){ siA[wid][0] = li; siA[wid][1] = ri; }
  }

  // ---------- prefix-sum queries: Q[q] = sum x[0..q] (one warp per query) ----------
  {
    int qi = wid;
#pragma unroll
    for (int r = 0; r < 3; ++r, qi += 4){
      if (qi < 12){
        int q = sb_q[qi];
        float acc = 0.f;
        if (q >= 0){
          int cq = q >> 5;                      // owning chunk (thread)
#pragma unroll
          for (int m = 0; m < 4; ++m){
            int tt = lane + (m << 6);
            float p = psum[tt];
            acc += (tt < cq) ? p : 0.f;
          }
          if (lane < 32 && lane <= (q & 31)){   // partial chunk
            f2 cc = cx[cpad((cq << 4) + (lane >> 1))];
            acc += (lane & 1) ? cc.y : cc.x;
          }
        }
        acc = wsumf(acc);
        if (lane == 0) qres[qi] = acc;
      }
    }
  }
  __syncthreads();                       // S3b: all signal reads done

  // ---------- FFT: 3 register radix-16 stages (N=4096) ----------
  f2 a[16];
  // stage 0: k = t + 256 d, w = W4096^t
#pragma unroll
  for (int d = 0; d < 16; ++d) a[d] = cx[cpad(t + (d << 8))];
  { float sr, si;
    __sincosf(-1.5339807878856412e-3f * (float)t, &si, &sr);     // -2pi/4096
    dft16(a, mkf2(sr, si)); }
#pragma unroll
  for (int d = 0; d < 16; ++d) cx[cpad(t + (d << 8))] = a[d];
  __syncthreads();                       // S4
  // stage 1: k = (t>>4)*256 + (t&15) + 16 d, w = W256^(t&15)
  { const int i0 = ((t >> 4) << 8) + (t & 15);
#pragma unroll
    for (int d = 0; d < 16; ++d) a[d] = cx[cpad(i0 + (d << 4))];
    float sr, si;
    __sincosf(-2.4543692606170259e-2f * (float)(t & 15), &si, &sr);  // -2pi/256
    dft16(a, mkf2(sr, si));
#pragma unroll
    for (int d = 0; d < 16; ++d) cx[cpad(i0 + (d << 4))] = a[d];
  }
  __syncthreads();                       // S5
  // stage 2: k = 16 t + d, w = 1; scatter-write to natural order
#pragma unroll
  for (int d = 0; d < 16; ++d) a[d] = cx[cpad((t << 4) + d)];
  __syncthreads();                       // S6: all reads done before scattered writes
  dft16(a, mkf2(1.f, 0.f));
  const int M = ((t & 3) << 6) | (((t >> 2) & 3) << 4) | (((t >> 4) & 3) << 2) | (t >> 6);
#pragma unroll
  for (int s = 0; s < 16; ++s){
    const int r = ((s & 3) << 2) | (s >> 2);
    cx[cpad((s << 8) + M)] = a[r];       // == drev12(16t+r): natural order
  }
  __syncthreads();                       // S7: natural-order Z[k] in cx

  // ---------- fused Hermitian unpack + |X| sum (own regs + partner reads) ----------
  float msum = 0.f;
  { float sr, si;
    __sincosf(-7.6699039394282058e-4f * (float)M, &si, &sr);     // W8192^M
    f2 cw = mkf2(sr, si);
    const f2 WS = mkf2(0.98078528040323044f, -0.19509032201612827f); // W8192^256
#pragma unroll
    for (int s = 0; s < 16; ++s){
      const int r = ((s & 3) << 2) | (s >> 2);
      const f2 z = a[r];                                   // Z[256 s + M]
      const int kk = (((15 - s) << 8) + 256 - M) & (NH - 1);
      const f2 y = cx[cpad(kk)];                           // Z[(4096-k) mod 4096]
      f2 e = z + mkf2(y.x, -y.y);                          // 2 E
      f2 o = nimul(z) + mkf2(y.y, y.x);                    // 2 O
      f2 tt = cmul(o, cw);
      f2 x1 = e + tt, x2 = e - tt;                         // 2 X[k], 2 X[k+4096]
      f2 q1 = x1 * x1, q2 = x2 * x2;
      msum += __builtin_amdgcn_sqrtf(q1.x + q1.y);
      msum += __builtin_amdgcn_sqrtf(q2.x + q2.y);
      cw = cmul(cw, WS);
    }
  }
  msum = wsumf(msum);
  if (lane == 0) sdA[wid][3] = msum;
  __syncthreads();                       // S8

  if (t == 0){
    float msT = sdA[0][3] + sdA[1][3] + sdA[2][3] + sdA[3][3];
    int liT = min(min(siA[0][0], siA[1][0]), min(siA[2][0], siA[3][0]));
    int riT = max(max(siA[0][1], siA[1][1]), max(siA[2][1], siA[3][1]));
    double n = (double)LFULL;
    double var = (t0_sumsq - t0_sum * t0_sum / n) / (n - 1.0);
    float F0 = t0_mx, F1 = t0_mx - t0_mn, F2 = (float)var, F3 = (float)sqrt(var);
    float F4 = msT * (1.f / 16384.f);    // /2 (fold) /8192 (mean)
    float F5 = 0.f, F6 = 0.f, F7 = 0.f, F8 = 0.f, F9 = 0.f;
    if (t0_valid){
      const float C = 0.5f / 30.0f;
      F5 = C * ((qres[2]  - qres[0]) + (qres[3]  - qres[1]));
      F6 = C * ((qres[6]  - qres[4]) + (qres[7]  - qres[5]));
      F8 = C * ((qres[10] - qres[8]) + (qres[11] - qres[9]));
      F7 = t0_ph;
      int LI = (liT == BIGI) ? sb_i[1] : liT;
      int RI = (riT == -1)   ? sb_i[0] : riT;
      F9 = (float)(RI - LI) / 30.0f;
    }
    float* __restrict__ o = out + (size_t)b * 10;
    o[0]=F0; o[1]=F1; o[2]=F2; o[3]=F3; o[4]=F4;
    o[5]=F5; o[6]=F6; o[7]=F7; o[8]=F8; o[9]=F9;
  }
}

extern "C" void kernel_launch(void* const* d_in, const int* in_sizes, int n_in,
                              void* d_out, int out_size, void* d_ws, size_t ws_size,
                              hipStream_t stream){
  const float* x = (const float*)d_in[0];
  float* out = (float*)d_out;
  int nrows = in_sizes[0] / LFULL;
  hipLaunchKernelGGL(feat_kernel, dim3(nrows), dim3(256), 0, stream, x, out);
}

// Round 7
// 108.411 us; speedup vs baseline: 1.1393x; 1.0214x over previous
//
#include <hip/hip_runtime.h>
#include <cmath>

#define LFULL 8192
#define NH    4096
#define BIGI  8192

typedef float f2 __attribute__((ext_vector_type(2)));

__device__ __forceinline__ f2 mkf2(float a, float b){ f2 r; r.x = a; r.y = b; return r; }

// ---- forced-packed complex primitives (VOP3P) ----
// cmul: (a.x b.x - a.y b.y, a.x b.y + a.y b.x) -- 2 instructions
__device__ __forceinline__ f2 cmul(f2 a, f2 b){
  f2 d;
  asm("v_pk_mul_f32 %0, %1, %2 op_sel:[0,0] op_sel_hi:[0,1]\n\t"
      "v_pk_fma_f32 %0, %1, %2, %0 op_sel:[1,1,0] op_sel_hi:[1,0,1] neg_lo:[0,1,0]"
      : "=&v"(d) : "v"(a), "v"(b));
  return d;
}
// a + (-i)b = (a.x + b.y, a.y - b.x)
__device__ __forceinline__ f2 addni(f2 a, f2 b){
  f2 d;
  asm("v_pk_add_f32 %0, %1, %2 op_sel:[0,1] op_sel_hi:[1,0] neg_hi:[0,1]"
      : "=v"(d) : "v"(a), "v"(b));
  return d;
}
// a - (-i)b = (a.x - b.y, a.y + b.x)
__device__ __forceinline__ f2 subni(f2 a, f2 b){
  f2 d;
  asm("v_pk_add_f32 %0, %1, %2 op_sel:[0,1] op_sel_hi:[1,0] neg_lo:[0,1]"
      : "=v"(d) : "v"(a), "v"(b));
  return d;
}
// a + conj(b) = (a.x + b.x, a.y - b.y)
__device__ __forceinline__ f2 cjadd(f2 a, f2 b){
  f2 d;
  asm("v_pk_add_f32 %0, %1, %2 neg_hi:[0,1]" : "=v"(d) : "v"(a), "v"(b));
  return d;
}
// (-i)a + swap(b) = (a.y + b.y, -a.x + b.x)
__device__ __forceinline__ f2 niswp(f2 a, f2 b){
  f2 d;
  asm("v_pk_add_f32 %0, %1, %2 op_sel:[1,1] op_sel_hi:[0,0] neg_hi:[1,0]"
      : "=v"(d) : "v"(a), "v"(b));
  return d;
}
// (-i)*t
__device__ __forceinline__ f2 nimul(f2 t){ return mkf2(t.y, -t.x); }

// complex index -> padded complex index (+1 complex per 16)
__device__ __forceinline__ int cpad(int k){ return k + (k >> 4); }

__device__ __forceinline__ float wmaxf(float v){
#pragma unroll
  for (int o = 32; o; o >>= 1) v = fmaxf(v, __shfl_xor(v, o));
  return v;
}
__device__ __forceinline__ float wminf(float v){
#pragma unroll
  for (int o = 32; o; o >>= 1) v = fminf(v, __shfl_xor(v, o));
  return v;
}
__device__ __forceinline__ float wsumf(float v){
#pragma unroll
  for (int o = 32; o; o >>= 1) v += __shfl_xor(v, o);
  return v;
}
__device__ __forceinline__ int wsumi(int v){
#pragma unroll
  for (int o = 32; o; o >>= 1) v += __shfl_xor(v, o);
  return v;
}
__device__ __forceinline__ int wmini(int v){
#pragma unroll
  for (int o = 32; o; o >>= 1) v = min(v, __shfl_xor(v, o));
  return v;
}
__device__ __forceinline__ int wmaxi(int v){
#pragma unroll
  for (int o = 32; o; o >>= 1) v = max(v, __shfl_xor(v, o));
  return v;
}
__device__ __forceinline__ unsigned mb32(int n){
  return (n <= 0) ? 0u : (n >= 32) ? 0xffffffffu : ((1u << n) - 1u);
}

// 16-point DFT (two radix-4 DIF layers), output twiddle folded:
// out[r] = w^r * DFT16(in)_r.  Same math as Round 5/6 (verified); packed asm.
template<int TW>
__device__ __forceinline__ void dft16t(f2* v, f2 w){
  const f2 W1 = mkf2( 0.92387953251128676f, -0.38268343236508977f);
  const f2 W2 = mkf2( 0.70710678118654752f, -0.70710678118654752f);
  const f2 W3 = mkf2( 0.38268343236508977f, -0.92387953251128676f);
  const f2 W6 = mkf2(-0.70710678118654752f, -0.70710678118654752f);
  const f2 W9 = mkf2(-0.92387953251128676f,  0.38268343236508977f);
  f2 w2, w3;
  f2 T1[4], T2[4], T3[4];
  if (TW){
    w2 = cmul(w, w); w3 = cmul(w2, w);
    T1[0] = w;           T2[0] = w2;          T3[0] = w3;
    T1[1] = cmul(w, W1); T2[1] = cmul(w2, W2); T3[1] = cmul(w3, W3);
    T1[2] = cmul(w, W2); T2[2] = nimul(w2);    T3[2] = cmul(w3, W6);
    T1[3] = cmul(w, W3); T2[3] = cmul(w2, W6); T3[3] = cmul(w3, W9);
  }
#pragma unroll
  for (int d = 0; d < 4; ++d){
    f2 t0 = v[d]     + v[d+8];
    f2 t1 = v[d]     - v[d+8];
    f2 t2 = v[d+4]   + v[d+12];
    f2 t3 = v[d+4]   - v[d+12];
    f2 u0 = t0 + t2;
    f2 u2 = t0 - t2;
    f2 u1 = addni(t1, t3);
    f2 u3 = subni(t1, t3);
    v[d] = u0;
    if (TW){
      v[d+4]  = cmul(u1, T1[d]);
      v[d+8]  = cmul(u2, T2[d]);
      v[d+12] = cmul(u3, T3[d]);
    } else {
      v[d+4]  = (d==0) ? u1 : cmul(u1, (d==1) ? W1 : (d==2) ? W2 : W3);
      v[d+8]  = (d==0) ? u2 : (d==2) ? nimul(u2) : cmul(u2, (d==1) ? W2 : W6);
      v[d+12] = (d==0) ? u3 : cmul(u3, (d==1) ? W3 : (d==2) ? W6 : W9);
    }
  }
  f2 U1, U2, U3;
  if (TW){ U1 = cmul(w2, w2); U2 = cmul(U1, U1); U3 = cmul(U2, U1); }
#pragma unroll
  for (int g = 0; g < 4; ++g){
    const int i0 = 4*g;
    f2 t0 = v[i0]   + v[i0+2];
    f2 t1 = v[i0]   - v[i0+2];
    f2 t2 = v[i0+1] + v[i0+3];
    f2 t3 = v[i0+1] - v[i0+3];
    f2 z0 = t0 + t2;
    f2 z1 = addni(t1, t3);
    f2 z2 = t0 - t2;
    f2 z3 = subni(t1, t3);
    v[i0] = z0;
    if (TW){
      v[i0+1] = cmul(z1, U1);
      v[i0+2] = cmul(z2, U2);
      v[i0+3] = cmul(z3, U3);
    } else {
      v[i0+1] = z1; v[i0+2] = z2; v[i0+3] = z3;
    }
  }
}

__global__ __launch_bounds__(256, 4)
void feat_kernel(const float* __restrict__ x, float* __restrict__ out){
  const int b = blockIdx.x;
  const float* __restrict__ row = x + (size_t)b * LFULL;

  __shared__ f2    cx[4352];             // 4096 complex + 256 pad
  __shared__ float psum[256];            // per-thread 32-sample chunk sums
  __shared__ float sdA[4][4];            // [0]=sum [1]=sumsq [3]=msum
  __shared__ float sfA[4][2];            // mx, mn
  __shared__ int   siA[4][8];            // 0..5: A-phase partials; 6,7: li,ri
  __shared__ float qres[12];

  const int t    = threadIdx.x;
  const int lane = t & 63;
  const int wid  = t >> 6;
  const int base = t << 5;

  // ---------- load 32 contiguous samples as 16 complex pairs ----------
  f2 vv[16];
  const float4* __restrict__ rp = (const float4*)(row + base);
#pragma unroll
  for (int q = 0; q < 8; ++q){
    float4 f = rp[q];
    vv[2*q]   = mkf2(f.x, f.y);
    vv[2*q+1] = mkf2(f.z, f.w);
  }
#pragma unroll
  for (int c = 0; c < 16; ++c)
    cx[cpad((t << 4) + c)] = vv[c];
  __syncthreads();                       // S1

  const float xm_prev = (t > 0)   ? cx[cpad((t << 4) - 1)].y  : vv[0].x;
  const float xp_next = (t < 255) ? cx[cpad((t << 4) + 16)].x : vv[15].y;

  // ---------- Phase A: packed stats + peak/valley bitmasks ----------
  f2 mx2 = mkf2(-INFINITY, -INFINITY), mn2 = mkf2(INFINITY, INFINITY);
  f2 sum2 = mkf2(0.f, 0.f), ss2 = mkf2(0.f, 0.f);
  unsigned pmask = 0u, vmask = 0u;
  float dprev = vv[0].x - xm_prev;
#pragma unroll
  for (int c = 0; c < 16; ++c){
    const f2 u = vv[c];
    mx2 = __builtin_elementwise_max(mx2, u);
    mn2 = __builtin_elementwise_min(mn2, u);
    sum2 += u;
    ss2 = __builtin_elementwise_fma(u, u, ss2);
    const float d0 = u.y - u.x;
    const float xnext = (c < 15) ? vv[(c + 1) & 15].x : xp_next;
    const float d1 = xnext - u.y;
    pmask |= ((dprev > 0.f) & (d0 < 0.f)) ? (1u << (2*c))   : 0u;
    vmask |= ((dprev < 0.f) & (d0 > 0.f)) ? (1u << (2*c))   : 0u;
    pmask |= ((d0 > 0.f) & (d1 < 0.f))    ? (1u << (2*c+1)) : 0u;
    vmask |= ((d0 < 0.f) & (d1 > 0.f))    ? (1u << (2*c+1)) : 0u;
    dprev = d1;
  }
  if (t == 0)  { pmask &= ~1u;          vmask &= ~1u; }
  if (t == 255){ pmask &= 0x7fffffffu;  vmask &= 0x7fffffffu; }
  float csum = sum2.x + sum2.y;
  psum[t] = csum;

  float mx = fmaxf(mx2.x, mx2.y), mn = fminf(mn2.x, mn2.y);
  float sum = csum, sumsq = ss2.x + ss2.y;
  int npk = __popc(pmask), nvl = __popc(vmask);
  int p0 = pmask ? base + __builtin_ctz(pmask) : BIGI;
  int va = vmask ? base + __builtin_ctz(vmask) : BIGI;
  unsigned vm2m = vmask & (vmask - 1u);
  int vb = vm2m ? base + __builtin_ctz(vm2m) : BIGI;
  int vl = vmask ? base + 31 - __builtin_clz(vmask) : -1;

  mx = wmaxf(mx); mn = wminf(mn);
  sum = wsumf(sum); sumsq = wsumf(sumsq);
  npk = wsumi(npk); nvl = wsumi(nvl);
  p0 = wmini(p0); vl = wmaxi(vl);
#pragma unroll
  for (int o = 32; o; o >>= 1){          // two smallest valley indices
    int oa = __shfl_xor(va, o), ob = __shfl_xor(vb, o);
    int na = min(va, oa);
    int nb = min(max(va, oa), min(vb, ob));
    va = na; vb = nb;
  }
  if (lane == 0){
    sfA[wid][0] = mx;  sfA[wid][1] = mn;
    sdA[wid][0] = sum; sdA[wid][1] = sumsq;
    siA[wid][0] = npk; siA[wid][1] = nvl; siA[wid][2] = p0;
    siA[wid][3] = va;  siA[wid][4] = vb;  siA[wid][5] = vl;
  }
  __syncthreads();                       // S2

  // ---------- redundant cross-warp combine (all threads, no serialization) ----
  int npkT = siA[0][0], nvlT = siA[0][1], p0T = siA[0][2];
  int vaT  = siA[0][3], vbT  = siA[0][4], vlT = siA[0][5];
#pragma unroll
  for (int w = 1; w < 4; ++w){
    npkT += siA[w][0]; nvlT += siA[w][1];
    p0T = min(p0T, siA[w][2]);
    int oa = siA[w][3], ob = siA[w][4];
    int na = min(vaT, oa);
    int nb = min(max(vaT, oa), min(vbT, ob));
    vaT = na; vbT = nb;
    vlT = max(vlT, siA[w][5]);
  }
  const int valid = (npkT >= 1) && (nvlT >= 2);
  const int P0 = valid ? p0T : 0, V0 = valid ? vaT : 0;
  const int V1 = valid ? vbT : 0, VL = valid ? vlT : 0;
  f2 cp = cx[cpad(P0 >> 1)], cv = cx[cpad(V0 >> 1)];
  const float xp0 = (P0 & 1) ? cp.y : cp.x;
  const float xv0 = (V0 & 1) ? cv.y : cv.x;
  const float hh  = 0.5f * (xp0 + xv0);
  const float phv = xp0 - xv0;
  const int bu1 = max(VL - 2, V0 - 1);
  const int bu2 = max(V1 - 2, P0 - 1);
  const int bu3 = max(P0 - 2, V0 - 1);

  // ---------- half-height li/ri via 32-bit bitmask ----------
  {
    unsigned hhm = 0u;
#pragma unroll
    for (int c = 0; c < 16; ++c){
      hhm |= (vv[c].x >= hh) ? (1u << (2*c))   : 0u;
      hhm |= (vv[c].y >= hh) ? (1u << (2*c+1)) : 0u;
    }
    unsigned rml = mb32(P0 - base)     & ~mb32(V0 - base);      // [V0, P0)
    unsigned rmr = mb32(P0 + 1 - base) & ~mb32(V0 + 1 - base);  // (V0, P0]
    unsigned ml  = hhm & rml, mr2 = hhm & rmr;
    int li = ml  ? base + __builtin_ctz(ml) : BIGI;
    int ri = mr2 ? base + 31 - __builtin_clz(mr2) : -1;
    li = wmini(li); ri = wmaxi(ri);
    if (lane == 0){ siA[wid][6] = li; siA[wid][7] = ri; }
  }

  // ---------- prefix-sum queries (per-warp, wave-uniform index choice) ----------
  {
    int qq[3];
    if      (wid == 0){ qq[0] = V0 - 1; qq[1] = P0 - 1; qq[2] = V0 - 1; }
    else if (wid == 1){ qq[0] = V0;     qq[1] = P0;     qq[2] = V0;     }
    else if (wid == 2){ qq[0] = bu1;    qq[1] = bu2;    qq[2] = bu3;    }
    else              { qq[0] = bu1+1;  qq[1] = bu2+1;  qq[2] = bu3+1;  }
#pragma unroll
    for (int r = 0; r < 3; ++r){
      int q = qq[r];
      float acc = 0.f;
      if (q >= 0){
        int cq = q >> 5;
#pragma unroll
        for (int m = 0; m < 4; ++m){
          int tt = lane + (m << 6);
          float p = psum[tt];
          acc += (tt < cq) ? p : 0.f;
        }
        if (lane < 32 && lane <= (q & 31)){
          f2 cc = cx[cpad((cq << 4) + (lane >> 1))];
          acc += (lane & 1) ? cc.y : cc.x;
        }
      }
      acc = wsumf(acc);
      if (lane == 0) qres[wid + 4*r] = acc;
    }
  }

  // ---------- FFT stage 0 (reads signal; compute overlapped, writeback gated) ----
  f2 a[16];
#pragma unroll
  for (int d = 0; d < 16; ++d) a[d] = cx[cpad(t + (d << 8))];
  { float sr0, si0;
    __sincosf(-1.5339807878856412e-3f * (float)t, &si0, &sr0);   // -2pi/4096
    dft16t<1>(a, mkf2(sr0, si0)); }
  __syncthreads();                       // S3b: all signal reads complete
#pragma unroll
  for (int d = 0; d < 16; ++d) cx[cpad(t + (d << 8))] = a[d];
  __syncthreads();                       // S4

  // stage 1: k = (t>>4)*256 + (t&15) + 16 d, w = W256^(t&15)
  { const int i0 = ((t >> 4) << 8) + (t & 15);
#pragma unroll
    for (int d = 0; d < 16; ++d) a[d] = cx[cpad(i0 + (d << 4))];
    float sr1, si1;
    __sincosf(-2.4543692606170259e-2f * (float)(t & 15), &si1, &sr1);  // -2pi/256
    dft16t<1>(a, mkf2(sr1, si1));
#pragma unroll
    for (int d = 0; d < 16; ++d) cx[cpad(i0 + (d << 4))] = a[d];
  }
  __syncthreads();                       // S5
  // stage 2: k = 16 t + d, w = 1; scatter to natural order
#pragma unroll
  for (int d = 0; d < 16; ++d) a[d] = cx[cpad((t << 4) + d)];
  __syncthreads();                       // S6: reads done before scattered writes
  dft16t<0>(a, mkf2(1.f, 0.f));
  const int M = ((t & 3) << 6) | (((t >> 2) & 3) << 4) | (((t >> 4) & 3) << 2) | (t >> 6);
#pragma unroll
  for (int s = 0; s < 16; ++s){
    const int r = ((s & 3) << 2) | (s >> 2);
    cx[cpad((s << 8) + M)] = a[r];       // natural-order Z
  }
  __syncthreads();                       // S7

  // ---------- fused Hermitian unpack + |X| sum ----------
  float msum = 0.f;
  { float sr2, si2;
    __sincosf(-7.6699039394282058e-4f * (float)M, &si2, &sr2);   // W8192^M
    f2 cw = mkf2(sr2, si2);
    const f2 WS = mkf2(0.98078528040323044f, -0.19509032201612827f); // W8192^256
#pragma unroll
    for (int s = 0; s < 16; ++s){
      const int r = ((s & 3) << 2) | (s >> 2);
      const f2 z = a[r];                                   // Z[256 s + M]
      const int kk = (((15 - s) << 8) + 256 - M) & (NH - 1);
      const f2 y = cx[cpad(kk)];                           // Z[(4096-k) mod 4096]
      f2 e  = cjadd(z, y);                                 // 2E
      f2 o  = niswp(z, y);                                 // 2O
      f2 tt = cmul(o, cw);
      f2 x1 = e + tt, x2 = e - tt;                         // 2X[k], 2X[k+4096]
      f2 q1 = x1 * x1, q2 = x2 * x2;
      msum += __builtin_amdgcn_sqrtf(q1.x + q1.y);
      msum += __builtin_amdgcn_sqrtf(q2.x + q2.y);
      cw = cmul(cw, WS);
    }
  }
  msum = wsumf(msum);
  if (lane == 0) sdA[wid][3] = msum;
  __syncthreads();                       // S8

  if (t == 0){
    float mxT = fmaxf(fmaxf(sfA[0][0], sfA[1][0]), fmaxf(sfA[2][0], sfA[3][0]));
    float mnT = fminf(fminf(sfA[0][1], sfA[1][1]), fminf(sfA[2][1], sfA[3][1]));
    double dsum = (double)sdA[0][0] + sdA[1][0] + sdA[2][0] + sdA[3][0];
    double dss  = (double)sdA[0][1] + sdA[1][1] + sdA[2][1] + sdA[3][1];
    float msT = sdA[0][3] + sdA[1][3] + sdA[2][3] + sdA[3][3];
    int liT = min(min(siA[0][6], siA[1][6]), min(siA[2][6], siA[3][6]));
    int riT = max(max(siA[0][7], siA[1][7]), max(siA[2][7], siA[3][7]));
    double n = (double)LFULL;
    double var = (dss - dsum * dsum / n) / (n - 1.0);
    float F0 = mxT, F1 = mxT - mnT, F2 = (float)var, F3 = (float)sqrt(var);
    float F4 = msT * (1.f / 16384.f);    // /2 (fold) /8192 (mean)
    float F5 = 0.f, F6 = 0.f, F7 = 0.f, F8 = 0.f, F9 = 0.f;
    if (valid){
      const float C = 0.5f / 30.0f;
      F5 = C * ((qres[2]  - qres[0]) + (qres[3]  - qres[1]));
      F6 = C * ((qres[6]  - qres[4]) + (qres[7]  - qres[5]));
      F8 = C * ((qres[10] - qres[8]) + (qres[11] - qres[9]));
      F7 = phv;
      int LI = (liT == BIGI) ? V0 : liT;
      int RI = (riT == -1)   ? P0 : riT;
      F9 = (float)(RI - LI) / 30.0f;
    }
    float* __restrict__ o = out + (size_t)b * 10;
    o[0]=F0; o[1]=F1; o[2]=F2; o[3]=F3; o[4]=F4;
    o[5]=F5; o[6]=F6; o[7]=F7; o[8]=F8; o[9]=F9;
  }
}

extern "C" void kernel_launch(void* const* d_in, const int* in_sizes, int n_in,
                              void* d_out, int out_size, void* d_ws, size_t ws_size,
                              hipStream_t stream){
  const float* x = (const float*)d_in[0];
  float* out = (float*)d_out;
  int nrows = in_sizes[0] / LFULL;
  hipLaunchKernelGGL(feat_kernel, dim3(nrows), dim3(256), 0, stream, x, out);
}